// Round 10
// baseline (284.986 us; speedup 1.0000x reference)
//
#include <hip/hip_runtime.h>

#define N_SAMP   1024
#define IN_F     512
#define OUT_F    512
#define N_HEADS  32
#define N_SPLITS 4
#define DELTA_SCALE 0.1f

__device__ __forceinline__ void fma4(float4& a, float x, const float4& w) {
    a.x += x * w.x; a.y += x * w.y; a.z += x * w.z; a.w += x * w.w;
}
__device__ __forceinline__ void add4(float4& a, const float4& b) {
    a.x += b.x; a.y += b.y; a.z += b.z; a.w += b.w;
}

// R10 structure. Thread = (ct = col-quad 0..31, kq = lane bit5, wave role).
//  - kq k-split lives INSIDE the wave -> reduction is one __shfl_xor(,32)
//    per acc component: the 64 KB LDS "Red" buffer of R9 is gone (LDS 37 KB).
//  - base block  = (head, 128-col tile): waves = 4 sample-groups (jg), J=64,
//    JT=16. W quad-row re-read by 4 jg waves = L1 hits, affordable (VALU-heavy).
//  - delta block = (combo): waves = 4 col-quarters (c0 = wave*128), J=16,
//    JT=16 -> every W load unique, no redundant L1 traffic, W read once.
//  - distance-2 period-4 register pipeline rA..rD (constant indices only --
//    R7/R8's runtime-indexed rb[] scratch demotion is the known trap; clamped
//    tail prefetches are redundant L1 hits). 8-12 loads in flight/thread
//    self-hides ~900cyc HBM latency at 1 wave/SIMD.
//  - sole-owner stores; delta writes raw partials to ws (combine applies 0.1)
//    so both roles run concurrently in one dispatch.
template <int JCOV, int KC, bool DELTA>
__device__ __forceinline__ void role_pass(
    const float* __restrict__ X, const int* __restrict__ head_ix,
    const int* __restrict__ split_ix, const float* __restrict__ Wslice,
    const float* __restrict__ bias_g, float* __restrict__ dst,
    int g, int c0, int sampleBase, float* buf, int* list, int* wsum)
{
    constexpr int NST = KC / 8;        // 4-row steps per chunk per thread (k-half)
    constexpr int NCH = IN_F / KC;     // staged X chunks
    constexpr int QW  = KC / 4;        // float4 per staged X row

    const int tid  = threadIdx.x;
    const int lane = tid & 63, wave = tid >> 6;
    const int ct   = tid & 31;
    const int kq   = (tid >> 5) & 1;

    // deterministic order-preserving compaction (all blocks of g agree)
    int run = 0;
    for (int r = 0; r < N_SAMP / 256; ++r) {
        const int i   = r * 256 + tid;
        const int key = DELTA ? head_ix[i] * N_SPLITS + split_ix[i] : head_ix[i];
        const bool hit = (key == g);
        const unsigned long long m = __ballot(hit);
        if (lane == 0) wsum[wave] = __popcll(m);
        __syncthreads();
        int base = run;
        for (int w = 0; w < 4; ++w)
            if (w < wave) base += wsum[w];
        if (hit)
            list[base + __popcll(m & ((1ULL << lane) - 1ULL))] = i;
        run += wsum[0] + wsum[1] + wsum[2] + wsum[3];
        __syncthreads();
    }
    const int total = run;
    if (total == 0) return;            // block-uniform

    float4 bv;
    if (!DELTA) bv = *(const float4*)(bias_g + c0 + ct * 4);

#define LDW(R, stx) {                                                        \
    const int sx_ = (stx) < NST ? (stx) : NST - 1;                           \
    const float* w_ = wp + (size_t)(sx_ * 4) * OUT_F;                        \
    R[0] = *(const float4*)(w_);                                             \
    R[1] = *(const float4*)(w_ + OUT_F);                                     \
    R[2] = *(const float4*)(w_ + 2 * OUT_F);                                 \
    R[3] = *(const float4*)(w_ + 3 * OUT_F); }
#define CONS(R, stx) {                                                       \
    _Pragma("unroll")                                                        \
    for (int j = 0; j < 16; ++j) {                                           \
        const float4 xv = *(const float4*)(xb + j * KC + (stx) * 4);         \
        fma4(acc[j], xv.x, R[0]); fma4(acc[j], xv.y, R[1]);                  \
        fma4(acc[j], xv.z, R[2]); fma4(acc[j], xv.w, R[3]); } }

    for (int s0 = 0; s0 < total; s0 += JCOV) {    // expected 1 iteration
        const int nc = min(total - s0, JCOV);

        float4 acc[16];
#pragma unroll
        for (int j = 0; j < 16; ++j) acc[j] = make_float4(0.f, 0.f, 0.f, 0.f);

        for (int ch = 0; ch < NCH; ++ch) {
            const int kc = ch * KC;
            __syncthreads();           // prior chunk fully consumed
            for (int i = tid; i < JCOV * QW; i += 256) {
                const int s = i / QW, q = i % QW;
                float4 v = make_float4(0.f, 0.f, 0.f, 0.f);
                if (s < nc)
                    v = *(const float4*)(X + (size_t)list[s0 + s] * IN_F + kc + q * 4);
                *(float4*)(&buf[s * KC + q * 4]) = v;
            }
            __syncthreads();

            const float* wp = Wslice + (size_t)(kc + kq * (KC / 2)) * OUT_F
                            + c0 + ct * 4;
            const float* xb = buf + (size_t)sampleBase * KC + kq * (KC / 2);

            float4 rA[4], rB[4], rC[4], rD[4];
            LDW(rA, 0); LDW(rB, 1);
            for (int st = 0; st < NST; st += 4) {   // NST % 4 == 0 (16 or 64)
                LDW(rC, st + 2);
                CONS(rA, st);
                LDW(rD, st + 3);
                CONS(rB, st + 1);
                LDW(rA, st + 4);
                CONS(rC, st + 2);
                LDW(rB, st + 5);
                CONS(rD, st + 3);
            }
        }

        // kq-reduce in-wave, then sole-owner store (lanes kq==0)
#pragma unroll
        for (int j = 0; j < 16; ++j) {
            acc[j].x += __shfl_xor(acc[j].x, 32);
            acc[j].y += __shfl_xor(acc[j].y, 32);
            acc[j].z += __shfl_xor(acc[j].z, 32);
            acc[j].w += __shfl_xor(acc[j].w, 32);
        }
        if (kq == 0) {
#pragma unroll
            for (int j = 0; j < 16; ++j) {
                const int slot = sampleBase + j;
                if (slot < nc) {
                    float* op = dst + (size_t)list[s0 + slot] * OUT_F + c0 + ct * 4;
                    float4 s = acc[j];
                    if (!DELTA) add4(s, bv);
                    *(float4*)op = s;
                }
            }
        }
    }
#undef LDW
#undef CONS
}

// 256 blocks, 1/CU. odd bid -> base (128: head x 4 tiles, J=64, jg=wave,
// out = acc + bias, covers every output). even bid -> delta (128: one per
// combo, waves = col-quarters, J=16, raw partials to ws). Roles have equal
// per-block work (~64 steps x 16 samples) -> balanced.
__global__ __launch_bounds__(256, 2) void lms_fused(
    const float* __restrict__ X, const int* __restrict__ head_ix,
    const int* __restrict__ split_ix, const float* __restrict__ W,
    const float* __restrict__ D, const float* __restrict__ bias,
    float* __restrict__ out, float* __restrict__ ws)
{
    __shared__ float buf[8192];        // 32 KB: Xs[64][128] or Xs[16][512]
    __shared__ int   list[N_SAMP];
    __shared__ int   wsum[4];

    const int bid  = blockIdx.x;
    const int wave = threadIdx.x >> 6;
    if (bid & 1) {
        const int id   = bid >> 1;               // 0..127
        const int head = id & 31, tile = id >> 5;
        role_pass<64, 128, false>(X, head_ix, split_ix,
            W + (size_t)head * IN_F * OUT_F, bias + (size_t)head * OUT_F,
            out, head, tile * 128, wave * 16, buf, list, wsum);
    } else {
        const int combo = bid >> 1;              // 0..127
        role_pass<16, 512, true>(X, head_ix, split_ix,
            D + (size_t)combo * IN_F * OUT_F, nullptr,
            ws, combo, wave * 128, 0, buf, list, wsum);
    }
}

// out += 0.1 * ws (every ws element written: each sample's combo is nonempty
// by construction; its block's 4 wave-quarters cover all 512 cols)
__global__ __launch_bounds__(256) void combine_kernel(
    float* __restrict__ out, const float* __restrict__ ws)
{
    const int i = blockIdx.x * 256 + threadIdx.x;
    float4 o = ((float4*)out)[i];
    const float4 d = ((const float4*)ws)[i];
    o.x += DELTA_SCALE * d.x; o.y += DELTA_SCALE * d.y;
    o.z += DELTA_SCALE * d.z; o.w += DELTA_SCALE * d.w;
    ((float4*)out)[i] = o;
}

extern "C" void kernel_launch(void* const* d_in, const int* in_sizes, int n_in,
                              void* d_out, int out_size, void* d_ws, size_t ws_size,
                              hipStream_t stream) {
    const float* X        = (const float*)d_in[0];
    const int*   head_ix  = (const int*)d_in[1];
    const int*   split_ix = (const int*)d_in[2];
    const float* W        = (const float*)d_in[3];
    const float* D        = (const float*)d_in[4];
    const float* bias     = (const float*)d_in[5];
    float*       out      = (float*)d_out;
    float*       ws       = (float*)d_ws;

    lms_fused<<<256, 256, 0, stream>>>(X, head_ix, split_ix, W, D, bias, out, ws);
    combine_kernel<<<(N_SAMP * OUT_F / 4) / 256, 256, 0, stream>>>(out, ws);
}